// Round 8
// baseline (324.677 us; speedup 1.0000x reference)
//
#include <hip/hip_runtime.h>
#include <hip/hip_bf16.h>

// Problem constants (from reference)
#define N_NODES   40000
#define N_EDGES   640000
#define F         128      // F_IN == HID == 128
#define N_GRAPHS  64
#define N_CLASSES 10

typedef short bf16x8 __attribute__((ext_vector_type(8)));
typedef float f32x4  __attribute__((ext_vector_type(4)));

// fp32 -> bf16 with round-to-nearest-even
__device__ __forceinline__ unsigned short f2bf(float f) {
    union { float f; unsigned u; } v; v.f = f;
    unsigned r = v.u + 0x7fffu + ((v.u >> 16) & 1u);
    return (unsigned short)(r >> 16);
}
__device__ __forceinline__ float bflo(unsigned u) { return __uint_as_float(u << 16); }
__device__ __forceinline__ float bfhi(unsigned u) { return __uint_as_float(u & 0xffff0000u); }
__device__ __forceinline__ unsigned pack2(float a, float b) {
    return (unsigned)f2bf(a) | ((unsigned)f2bf(b) << 16);
}

#define APITCH 136   // bf16 units; 272 B rows: 16B-aligned frags, bank-spread

// ---------------------------------------------------------------------------
// Precompute transposed bf16 weights: Wt_l[c][k] = bf16(W_l[k][c]), l=0..2.
__global__ void wcvt_kernel(const float* __restrict__ W1, const float* __restrict__ W2,
                            const float* __restrict__ W3, unsigned short* __restrict__ Wt) {
    int idx = blockIdx.x * 256 + threadIdx.x;          // 0 .. 3*16384-1
    int l = idx >> 14;
    int r = idx & 16383;
    int c = r >> 7, k = r & 127;
    const float* W = (l == 0) ? W1 : ((l == 1) ? W2 : W3);
    Wt[idx] = f2bf(W[k * 128 + c]);                    // write coalesced (k fast)
}

// ---------------------------------------------------------------------------
// CSR build step 2: single-block scan of deg -> rowptr & cursor, plus
// dis[v] = rsqrt(deg[v] + 1). Coalesced tiles of 4096 (1024 threads x int4).
__global__ __launch_bounds__(1024) void scan_kernel(
    const int* __restrict__ deg, int* __restrict__ rowptr,
    int* __restrict__ cursor, float* __restrict__ dis) {
    __shared__ int wsum[16];
    __shared__ int tile_total_s;
    const int tid  = threadIdx.x;
    const int lane = tid & 63;
    const int wave = tid >> 6;
    int running = 0;

    for (int t = 0; t < 10; ++t) {
        const int base = t * 4096 + tid * 4;
        int4 d = make_int4(0, 0, 0, 0);
        if (base < N_NODES) d = *(const int4*)(deg + base);
        const int sown = d.x + d.y + d.z + d.w;

        int s = sown;
#pragma unroll
        for (int off = 1; off < 64; off <<= 1) {
            int n = __shfl_up(s, off, 64);
            if (lane >= off) s += n;
        }
        if (lane == 63) wsum[wave] = s;
        __syncthreads();

        if (wave == 0) {
            int v = (lane < 16) ? wsum[lane] : 0;
#pragma unroll
            for (int off = 1; off < 16; off <<= 1) {
                int n = __shfl_up(v, off, 64);
                if (lane >= off) v += n;
            }
            if (lane < 16) wsum[lane] = v;
            if (lane == 15) tile_total_s = v;
        }
        __syncthreads();

        int excl = running + (wave ? wsum[wave - 1] : 0) + (s - sown);
        if (base < N_NODES) {
            int4 r;
            r.x = excl;
            r.y = r.x + d.x;
            r.z = r.y + d.y;
            r.w = r.z + d.z;
            *(int4*)(rowptr + base) = r;
            *(int4*)(cursor + base) = r;
            float4 di;
            di.x = rsqrtf((float)d.x + 1.0f);
            di.y = rsqrtf((float)d.y + 1.0f);
            di.z = rsqrtf((float)d.z + 1.0f);
            di.w = rsqrtf((float)d.w + 1.0f);
            *(float4*)(dis + base) = di;
        }
        running += tile_total_s;
        __syncthreads();
    }
}

// CSR build step 3: csr_src[cursor[col[e]]++] = row[e]
__global__ void fill_kernel(const int* __restrict__ row, const int* __restrict__ col,
                            int* __restrict__ cursor, int* __restrict__ csr_src) {
    int e = blockIdx.x * 256 + threadIdx.x;
    if (e < N_EDGES) {
        int pos = atomicAdd(&cursor[col[e]], 1);
        csr_src[pos] = row[e];
    }
}

// ---------------------------------------------------------------------------
// Per-node wave gather core: 64 lanes, part=lane&15 (16B chunk), quad=lane>>4
// (edge slot). Returns the aggregated row in quad0's acc[8] (fp32):
//   acc = sum_{e in in(v)} w_e * Hb[src_e]   (w_e = dis[src] if SCALED else 1)
template <bool SCALED>
__device__ __forceinline__ void gather_node(
    int v, const uint4* __restrict__ Hp, const int* __restrict__ csr_src,
    const int* __restrict__ rowptr, const int* __restrict__ deg,
    const float* __restrict__ dis, int lane, int part, int quad,
    float acc[8]) {
    const int start = rowptr[v];
    const int len   = deg[v];
#pragma unroll
    for (int i = 0; i < 8; ++i) acc[i] = 0.f;

    for (int j0 = 0; j0 < len; j0 += 64) {
        int m = len - j0; if (m > 64) m = 64;
        int nidx = (lane < m) ? csr_src[start + j0 + lane] : 0;
        for (int j = 0; j < m; j += 16) {
            int   r[4];
            float w[4];
            uint4 h[4];
#pragma unroll
            for (int u = 0; u < 4; ++u) {
                int  sl    = j + u * 4 + quad;
                bool valid = sl < m;
                r[u] = __shfl(nidx, valid ? sl : 0, 64);
                w[u] = valid ? (SCALED ? dis[r[u]] : 1.0f) : 0.0f;
            }
#pragma unroll
            for (int u = 0; u < 4; ++u) h[u] = Hp[(size_t)r[u] * 16];
#pragma unroll
            for (int u = 0; u < 4; ++u) {
                acc[0] = fmaf(bflo(h[u].x), w[u], acc[0]);
                acc[1] = fmaf(bfhi(h[u].x), w[u], acc[1]);
                acc[2] = fmaf(bflo(h[u].y), w[u], acc[2]);
                acc[3] = fmaf(bfhi(h[u].y), w[u], acc[3]);
                acc[4] = fmaf(bflo(h[u].z), w[u], acc[4]);
                acc[5] = fmaf(bfhi(h[u].z), w[u], acc[5]);
                acc[6] = fmaf(bflo(h[u].w), w[u], acc[6]);
                acc[7] = fmaf(bfhi(h[u].w), w[u], acc[7]);
            }
        }
    }
    // combine the 4 edge-slots (same cols at lane^16, lane^32)
#pragma unroll
    for (int i = 0; i < 8; ++i) {
        acc[i] += __shfl_xor(acc[i], 16, 64);
        acc[i] += __shfl_xor(acc[i], 32, 64);
    }
}

// ---------------------------------------------------------------------------
// Layer-1 MFMA GEMM: Hb[r][c] = bf16( x[r][:] @ W1 ), fused CSR degree count.
// Block: 256 threads / 4 waves, 64 rows. LDS 52 KB -> 3 blocks/CU.
// Fragment maps (verified m89/m92/m120): A: m=lane&15, k=quad*8+j;
// B^T: n=lane&15, k=quad*8+j; D: col=lane&15, row=quad*4+reg.
__global__ __launch_bounds__(256) void gemm1_kernel(
    const float* __restrict__ A, const unsigned short* __restrict__ Wt,
    unsigned short* __restrict__ Hb,
    const int* __restrict__ cnt_col, int* __restrict__ cnt_deg) {
    __shared__ unsigned short As[64 * APITCH];    // 17408 B
    __shared__ unsigned short Ws[128 * APITCH];   // 34816 B
    const int tid  = threadIdx.x;
    const int row0 = blockIdx.x * 64;

    {   // fused degree count for CSR build (deg pre-zeroed)
        int t = (blockIdx.x * 256 + tid) * 4;
#pragma unroll
        for (int j = 0; j < 4; ++j) atomicAdd(&cnt_deg[cnt_col[t + j]], 1);
    }

    // Stage Wt (bf16, 2048 uint4) -> Ws
    {
        const uint4* src = (const uint4*)Wt;
#pragma unroll
        for (int j = 0; j < 8; ++j) {
            int c4 = tid + j * 256;
            int c  = c4 >> 4;
            int o  = c4 & 15;
            *(uint4*)(Ws + c * APITCH + o * 8) = src[c4];
        }
    }
    // Stage A (fp32 -> bf16) -> As
#pragma unroll
    for (int j = 0; j < 8; ++j) {
        int c4 = tid + j * 256;
        int r  = c4 >> 5;
        int o  = (c4 & 31) << 2;
        float4 v = *(const float4*)(A + (size_t)(row0 + r) * F + o);
        uint2 p;
        p.x = pack2(v.x, v.y);
        p.y = pack2(v.z, v.w);
        *(uint2*)(As + r * APITCH + o) = p;
    }
    __syncthreads();

    const int lane = tid & 63;
    const int wave = tid >> 6;
    const int m16  = lane & 15;
    const int quad = lane >> 4;

    f32x4 acc[8];
#pragma unroll
    for (int t = 0; t < 8; ++t) acc[t] = (f32x4)(0.0f);

#pragma unroll
    for (int ks = 0; ks < 128; ks += 32) {
        bf16x8 a = *(const bf16x8*)(As + (wave * 16 + m16) * APITCH + ks + quad * 8);
#pragma unroll
        for (int t = 0; t < 8; ++t) {
            bf16x8 b = *(const bf16x8*)(Ws + (t * 16 + m16) * APITCH + ks + quad * 8);
            acc[t] = __builtin_amdgcn_mfma_f32_16x16x32_bf16(a, b, acc[t], 0, 0, 0);
        }
    }

    const int rbase = row0 + wave * 16 + quad * 4;
#pragma unroll
    for (int t = 0; t < 8; ++t) {
        int col = t * 16 + m16;
#pragma unroll
        for (int rg = 0; rg < 4; ++rg)
            Hb[(size_t)(rbase + rg) * F + col] = f2bf(acc[t][rg]);
    }
}

// ---------------------------------------------------------------------------
// Fused aggregation + MFMA GEMM (layers 2/3):
//   agg[v] = dis[v] * ( gather(Hb_in) + self )   (self w/ dis[v] if SCALED)
//   A-row  = relu(agg + bias)  -> bf16 -> As (LDS, staged by owning wave)
//   Hb_out = bf16( dis[r] * (A @ W) )            (pre-scaled for next gather)
template <bool SCALED>
__global__ __launch_bounds__(256) void fused_agg_gemm(
    const unsigned short* __restrict__ Hb_in, const unsigned short* __restrict__ Wt,
    const float* __restrict__ bias, const float* __restrict__ dis,
    const int* __restrict__ csr_src, const int* __restrict__ rowptr,
    const int* __restrict__ deg, unsigned short* __restrict__ Hb_out) {
    __shared__ unsigned short As[64 * APITCH];    // 17408 B
    __shared__ unsigned short Ws[128 * APITCH];   // 34816 B
    const int tid  = threadIdx.x;
    const int row0 = blockIdx.x * 64;
    const int lane = tid & 63;
    const int wave = tid >> 6;
    const int part = lane & 15;
    const int quad = lane >> 4;

    // Stage Wt -> Ws (all threads)
    {
        const uint4* src = (const uint4*)Wt;
#pragma unroll
        for (int j = 0; j < 8; ++j) {
            int c4 = tid + j * 256;
            int c  = c4 >> 4;
            int o  = c4 & 15;
            *(uint4*)(Ws + c * APITCH + o * 8) = src[c4];
        }
    }

    // Gather phase: wave w produces As rows w*16 .. w*16+15 (its own MFMA rows)
    const uint4* Hp = (const uint4*)Hb_in + part;
    for (int i = 0; i < 16; ++i) {
        const int v = row0 + wave * 16 + i;
        float acc[8];
        gather_node<SCALED>(v, Hp, csr_src, rowptr, deg, dis, lane, part, quad, acc);
        if (quad == 0) {
            const float dc  = dis[v];
            const float ws_ = SCALED ? dc : 1.0f;
            uint4 h = Hp[(size_t)v * 16];           // self-loop
            acc[0] = fmaf(bflo(h.x), ws_, acc[0]); acc[1] = fmaf(bfhi(h.x), ws_, acc[1]);
            acc[2] = fmaf(bflo(h.y), ws_, acc[2]); acc[3] = fmaf(bfhi(h.y), ws_, acc[3]);
            acc[4] = fmaf(bflo(h.z), ws_, acc[4]); acc[5] = fmaf(bfhi(h.z), ws_, acc[5]);
            acc[6] = fmaf(bflo(h.w), ws_, acc[6]); acc[7] = fmaf(bfhi(h.w), ws_, acc[7]);
            const int o = part << 3;
            float4 b0 = *(const float4*)(bias + o);
            float4 b1 = *(const float4*)(bias + o + 4);
            float f0 = fmaxf(fmaf(acc[0], dc, b0.x), 0.f);
            float f1 = fmaxf(fmaf(acc[1], dc, b0.y), 0.f);
            float f2 = fmaxf(fmaf(acc[2], dc, b0.z), 0.f);
            float f3 = fmaxf(fmaf(acc[3], dc, b0.w), 0.f);
            float f4_ = fmaxf(fmaf(acc[4], dc, b1.x), 0.f);
            float f5 = fmaxf(fmaf(acc[5], dc, b1.y), 0.f);
            float f6 = fmaxf(fmaf(acc[6], dc, b1.z), 0.f);
            float f7 = fmaxf(fmaf(acc[7], dc, b1.w), 0.f);
            uint4 pk;
            pk.x = pack2(f0, f1); pk.y = pack2(f2, f3);
            pk.z = pack2(f4_, f5); pk.w = pack2(f6, f7);
            *(uint4*)(As + (wave * 16 + i) * APITCH + o) = pk;
        }
    }
    __syncthreads();   // Ws staged by all; As rows by owning wave

    const int m16 = lane & 15;
    f32x4 acc[8];
#pragma unroll
    for (int t = 0; t < 8; ++t) acc[t] = (f32x4)(0.0f);

#pragma unroll
    for (int ks = 0; ks < 128; ks += 32) {
        bf16x8 a = *(const bf16x8*)(As + (wave * 16 + m16) * APITCH + ks + quad * 8);
#pragma unroll
        for (int t = 0; t < 8; ++t) {
            bf16x8 b = *(const bf16x8*)(Ws + (t * 16 + m16) * APITCH + ks + quad * 8);
            acc[t] = __builtin_amdgcn_mfma_f32_16x16x32_bf16(a, b, acc[t], 0, 0, 0);
        }
    }

    // Epilogue: pre-scale by dis[row] so the NEXT gather is scale-free.
    const int rbase = row0 + wave * 16 + quad * 4;
    float sc[4];
#pragma unroll
    for (int rg = 0; rg < 4; ++rg) sc[rg] = dis[rbase + rg];
#pragma unroll
    for (int t = 0; t < 8; ++t) {
        int col = t * 16 + m16;
#pragma unroll
        for (int rg = 0; rg < 4; ++rg)
            Hb_out[(size_t)(rbase + rg) * F + col] = f2bf(acc[t][rg] * sc[rg]);
    }
}

// ---------------------------------------------------------------------------
// Fused aggregation + pool: for each node v compute agg (gather of pre-scaled
// Hb3), then pooled[g] += relu(agg*dis[v] + b3), cnt[g] += 1. batch sorted ->
// per-wave run-length accumulate in quad0 registers, flush on g change.
#define PNODES 40
__global__ __launch_bounds__(256) void pool_gather_kernel(
    const unsigned short* __restrict__ Hb, const int* __restrict__ csr_src,
    const int* __restrict__ rowptr, const int* __restrict__ deg,
    const float* __restrict__ dis, const int* __restrict__ batch,
    const float* __restrict__ b3,
    float* __restrict__ pooled, float* __restrict__ cnt) {
    const int tid  = threadIdx.x;
    const int lane = tid & 63;
    const int wave = tid >> 6;
    const int part = lane & 15;
    const int quad = lane >> 4;
    const int base = blockIdx.x * PNODES;
    const uint4* Hp = (const uint4*)Hb + part;
    const int o = part << 3;

    float4 bb0 = *(const float4*)(b3 + o);
    float4 bb1 = *(const float4*)(b3 + o + 4);

    float pacc[8];
#pragma unroll
    for (int i = 0; i < 8; ++i) pacc[i] = 0.f;
    float c = 0.f;
    int gcur = -1;

    for (int j = wave; j < PNODES; j += 4) {
        const int v = base + j;          // 1000*40 = 40000, in range
        const int g = batch[v];
        float acc[8];
        gather_node<false>(v, Hp, csr_src, rowptr, deg, dis, lane, part, quad, acc);
        if (quad == 0) {
            if (g != gcur) {
                if (gcur >= 0) {
                    float* dst = pooled + gcur * F + o;
#pragma unroll
                    for (int i = 0; i < 8; ++i) atomicAdd(dst + i, pacc[i]);
                    if (part == 0) atomicAdd(&cnt[gcur], c);
                }
#pragma unroll
                for (int i = 0; i < 8; ++i) pacc[i] = 0.f;
                c = 0.f;
            }
            const float dc = dis[v];
            uint4 h = Hp[(size_t)v * 16];           // self-loop (pre-scaled)
            acc[0] += bflo(h.x); acc[1] += bfhi(h.x);
            acc[2] += bflo(h.y); acc[3] += bfhi(h.y);
            acc[4] += bflo(h.z); acc[5] += bfhi(h.z);
            acc[6] += bflo(h.w); acc[7] += bfhi(h.w);
            pacc[0] += fmaxf(fmaf(acc[0], dc, bb0.x), 0.f);
            pacc[1] += fmaxf(fmaf(acc[1], dc, bb0.y), 0.f);
            pacc[2] += fmaxf(fmaf(acc[2], dc, bb0.z), 0.f);
            pacc[3] += fmaxf(fmaf(acc[3], dc, bb0.w), 0.f);
            pacc[4] += fmaxf(fmaf(acc[4], dc, bb1.x), 0.f);
            pacc[5] += fmaxf(fmaf(acc[5], dc, bb1.y), 0.f);
            pacc[6] += fmaxf(fmaf(acc[6], dc, bb1.z), 0.f);
            pacc[7] += fmaxf(fmaf(acc[7], dc, bb1.w), 0.f);
            c += 1.f;
        }
        gcur = g;
    }
    if (quad == 0 && gcur >= 0) {
        float* dst = pooled + gcur * F + o;
#pragma unroll
        for (int i = 0; i < 8; ++i) atomicAdd(dst + i, pacc[i]);
        if (part == 0) atomicAdd(&cnt[gcur], c);
    }
}

// ---------------------------------------------------------------------------
// Head: out[g][c] = (sum_f pooled[g][f] * Wl[f][c]) / max(cnt[g],1) + bl[c]
__global__ void head_kernel(const float* __restrict__ pooled,
                            const float* __restrict__ cnt,
                            const float* __restrict__ Wl,
                            const float* __restrict__ bl,
                            float* __restrict__ out) {
    int tid = threadIdx.x;
    if (tid >= N_GRAPHS * N_CLASSES) return;
    int g = tid / N_CLASSES, c = tid % N_CLASSES;
    float acc = 0.f;
    for (int ff = 0; ff < F; ++ff)
        acc += pooled[g * F + ff] * Wl[ff * N_CLASSES + c];
    out[g * N_CLASSES + c] = acc / fmaxf(cnt[g], 1.f) + bl[c];
}

// ---------------------------------------------------------------------------
extern "C" void kernel_launch(void* const* d_in, const int* in_sizes, int n_in,
                              void* d_out, int out_size, void* d_ws, size_t ws_size,
                              hipStream_t stream) {
    const float* x    = (const float*)d_in[0];
    const int*   ei   = (const int*)d_in[1];     // [2][E]
    const int*   bat  = (const int*)d_in[2];
    const float* W1   = (const float*)d_in[3];
    const float* b1   = (const float*)d_in[4];
    const float* W2   = (const float*)d_in[5];
    const float* b2   = (const float*)d_in[6];
    const float* W3   = (const float*)d_in[7];
    const float* b3   = (const float*)d_in[8];
    const float* Wl   = (const float*)d_in[9];
    const float* bl   = (const float*)d_in[10];
    float* out = (float*)d_out;

    const int* row = ei;                 // edge_index[0] (source)
    const int* col = ei + N_EDGES;       // edge_index[1] (target)

    // Workspace layout (16B-aligned chunks)
    float*          ws      = (float*)d_ws;
    float*          dis     = ws;                                     // 40000 f
    unsigned short* Hb1     = (unsigned short*)(dis + N_NODES);       // 5.12M bf16
    unsigned short* Hb2     = Hb1 + (size_t)N_NODES * F;              // 5.12M bf16
    float*          pooled  = (float*)(Hb2 + (size_t)N_NODES * F);    // 8192 f
    float*          cnt     = pooled + N_GRAPHS * F;                  // 64 f
    int*            deg     = (int*)(cnt + N_GRAPHS);                 // 40000 i
    int*            rowptr  = deg + N_NODES;                          // 40000 i
    int*            cursor  = rowptr + N_NODES;                       // 40000 i
    int*            csr_src = cursor + N_NODES;                       // 640000 i
    unsigned short* Wtb     = (unsigned short*)(csr_src + N_EDGES);   // 3*16384 bf16

    const int edgeGrid = (N_EDGES + 255) / 256;      // 2500
    const int gemmGrid = N_NODES / 64;               // 625

    hipMemsetAsync(deg, 0, N_NODES * sizeof(int), stream);
    hipMemsetAsync(pooled, 0, (N_GRAPHS * F + N_GRAPHS) * sizeof(float), stream);
    wcvt_kernel<<<192, 256, 0, stream>>>(W1, W2, W3, Wtb);

    // --- layer 1 GEMM (unscaled bf16 H1, fused degree count), then CSR build ---
    gemm1_kernel<<<gemmGrid, 256, 0, stream>>>(x, Wtb, Hb1, col, deg);
    scan_kernel<<<1, 1024, 0, stream>>>(deg, rowptr, cursor, dis);
    fill_kernel<<<edgeGrid, 256, 0, stream>>>(row, col, cursor, csr_src);

    // --- layer 2: gather(H1, per-edge dis) + relu(+b1) + GEMM -> H2 (pre-scaled) ---
    fused_agg_gemm<true><<<gemmGrid, 256, 0, stream>>>(
        Hb1, Wtb + 16384, b1, dis, csr_src, rowptr, deg, Hb2);

    // --- layer 3: gather(H2) + relu(+b2) + GEMM -> H3 (pre-scaled) ---
    fused_agg_gemm<false><<<gemmGrid, 256, 0, stream>>>(
        Hb2, Wtb + 32768, b2, dis, csr_src, rowptr, deg, Hb1);

    // --- pool: gather(H3) + relu(+b3) + segment-sum ---
    pool_gather_kernel<<<N_NODES / PNODES, 256, 0, stream>>>(
        Hb1, csr_src, rowptr, deg, dis, bat, b3, pooled, cnt);
    head_kernel<<<1, N_GRAPHS * N_CLASSES, 0, stream>>>(pooled, cnt, Wl, bl, out);
}

// Round 9
// 301.461 us; speedup vs baseline: 1.0770x; 1.0770x over previous
//
#include <hip/hip_runtime.h>
#include <hip/hip_bf16.h>

// Problem constants (from reference)
#define N_NODES   40000
#define N_EDGES   640000
#define F         128      // F_IN == HID == 128
#define N_GRAPHS  64
#define N_CLASSES 10

typedef short bf16x8 __attribute__((ext_vector_type(8)));
typedef float f32x4  __attribute__((ext_vector_type(4)));

// fp32 -> bf16 with round-to-nearest-even
__device__ __forceinline__ unsigned short f2bf(float f) {
    union { float f; unsigned u; } v; v.f = f;
    unsigned r = v.u + 0x7fffu + ((v.u >> 16) & 1u);
    return (unsigned short)(r >> 16);
}
__device__ __forceinline__ float bflo(unsigned u) { return __uint_as_float(u << 16); }
__device__ __forceinline__ float bfhi(unsigned u) { return __uint_as_float(u & 0xffff0000u); }
__device__ __forceinline__ unsigned pack2(float a, float b) {
    return (unsigned)f2bf(a) | ((unsigned)f2bf(b) << 16);
}

#define APITCH 136   // bf16 units; 272 B rows: 16B-aligned frags, bank-spread

// ---------------------------------------------------------------------------
// Precompute transposed bf16 weights: Wt_l[c][k] = bf16(W_l[k][c]), l=0..2.
// Fused: zero deg (must run before gemm1's degree count).
__global__ void wcvt_kernel(const float* __restrict__ W1, const float* __restrict__ W2,
                            const float* __restrict__ W3, unsigned short* __restrict__ Wt,
                            int* __restrict__ deg) {
    int idx = blockIdx.x * 256 + threadIdx.x;          // 0 .. 3*16384-1
    if (idx < N_NODES) deg[idx] = 0;
    int l = idx >> 14;
    int r = idx & 16383;
    int c = r >> 7, k = r & 127;
    const float* W = (l == 0) ? W1 : ((l == 1) ? W2 : W3);
    Wt[idx] = f2bf(W[k * 128 + c]);                    // write coalesced (k fast)
}

// ---------------------------------------------------------------------------
// CSR build step 2: single-block scan of deg -> rowptr & cursor, plus
// dis[v] = rsqrt(deg[v] + 1). Coalesced tiles of 4096 (1024 threads x int4).
// Fused: zero pooled/cnt (consumed much later by pool_kernel).
__global__ __launch_bounds__(1024) void scan_kernel(
    const int* __restrict__ deg, int* __restrict__ rowptr,
    int* __restrict__ cursor, float* __restrict__ dis,
    float* __restrict__ pooled_zero) {
    __shared__ int wsum[16];
    __shared__ int tile_total_s;
    const int tid  = threadIdx.x;
    const int lane = tid & 63;
    const int wave = tid >> 6;

    for (int k = tid; k < N_GRAPHS * F + N_GRAPHS; k += 1024) pooled_zero[k] = 0.f;

    int running = 0;
    for (int t = 0; t < 10; ++t) {
        const int base = t * 4096 + tid * 4;
        int4 d = make_int4(0, 0, 0, 0);
        if (base < N_NODES) d = *(const int4*)(deg + base);
        const int sown = d.x + d.y + d.z + d.w;

        int s = sown;
#pragma unroll
        for (int off = 1; off < 64; off <<= 1) {
            int n = __shfl_up(s, off, 64);
            if (lane >= off) s += n;
        }
        if (lane == 63) wsum[wave] = s;
        __syncthreads();

        if (wave == 0) {
            int v = (lane < 16) ? wsum[lane] : 0;
#pragma unroll
            for (int off = 1; off < 16; off <<= 1) {
                int n = __shfl_up(v, off, 64);
                if (lane >= off) v += n;
            }
            if (lane < 16) wsum[lane] = v;
            if (lane == 15) tile_total_s = v;
        }
        __syncthreads();

        int excl = running + (wave ? wsum[wave - 1] : 0) + (s - sown);
        if (base < N_NODES) {
            int4 r;
            r.x = excl;
            r.y = r.x + d.x;
            r.z = r.y + d.y;
            r.w = r.z + d.z;
            *(int4*)(rowptr + base) = r;
            *(int4*)(cursor + base) = r;
            float4 di;
            di.x = rsqrtf((float)d.x + 1.0f);
            di.y = rsqrtf((float)d.y + 1.0f);
            di.z = rsqrtf((float)d.z + 1.0f);
            di.w = rsqrtf((float)d.w + 1.0f);
            *(float4*)(dis + base) = di;
        }
        running += tile_total_s;
        __syncthreads();
    }
}

// CSR build step 3: csr_src[cursor[col[e]]++] = row[e]
__global__ void fill_kernel(const int* __restrict__ row, const int* __restrict__ col,
                            int* __restrict__ cursor, int* __restrict__ csr_src) {
    int e = blockIdx.x * 256 + threadIdx.x;
    if (e < N_EDGES) {
        int pos = atomicAdd(&cursor[col[e]], 1);
        csr_src[pos] = row[e];
    }
}

// ---------------------------------------------------------------------------
// MFMA GEMM: Hb[r][c] = bf16( scale_r * relu?(A[r][:] + bias) @ W )
// A is fp32 (ABF16=false, layer 1) or bf16 (ABF16=true, layers 2/3, = AGGb).
// Wt = precomputed W^T bf16 [128 c][128 k]. Block: 256 threads / 4 waves,
// 64 rows. LDS 52 KB -> 3 blocks/CU.
// Fragment maps (verified m89/m92/m120): A: m=lane&15, k=quad*8+j;
// B^T: n=lane&15, k=quad*8+j; D: col=lane&15, row=quad*4+reg.
// Epilogue: D -> As (wave-private rows, no barrier) -> coalesced uint4 stores.
template<bool ABF16, bool RELU, bool SCALE, bool COUNT>
__global__ __launch_bounds__(256) void gemm_mfma(
    const void* __restrict__ Araw, const unsigned short* __restrict__ Wt,
    const float* __restrict__ bias, const float* __restrict__ dis,
    unsigned short* __restrict__ Hb,
    const int* __restrict__ cnt_col, int* __restrict__ cnt_deg) {
    __shared__ unsigned short As[64 * APITCH];    // 17408 B
    __shared__ unsigned short Ws[128 * APITCH];   // 34816 B
    const int tid  = threadIdx.x;
    const int row0 = blockIdx.x * 64;

    if (COUNT) {   // fused degree count for CSR build (deg pre-zeroed)
        int t = (blockIdx.x * 256 + tid) * 4;
#pragma unroll
        for (int j = 0; j < 4; ++j) atomicAdd(&cnt_deg[cnt_col[t + j]], 1);
    }

    // Stage Wt (bf16, 32768 B = 2048 uint4) -> Ws
    {
        const uint4* src = (const uint4*)Wt;
#pragma unroll
        for (int j = 0; j < 8; ++j) {
            int c4 = tid + j * 256;        // 0..2047; 16 uint4 per 128-bf16 row
            int c  = c4 >> 4;
            int o  = c4 & 15;
            *(uint4*)(Ws + c * APITCH + o * 8) = src[c4];
        }
    }
    // Stage A -> bias/relu -> bf16 -> As
    if (ABF16) {
        const uint4* src = (const uint4*)Araw;     // 16 uint4 per 128-bf16 row
#pragma unroll
        for (int j = 0; j < 4; ++j) {
            int c4 = tid + j * 256;        // 0..1023
            int r  = c4 >> 4;
            int p  = c4 & 15;
            int o  = p << 3;               // bf16 col offset (8 per chunk)
            uint4 hv = src[(size_t)(row0 + r) * 16 + p];
            float f0 = bflo(hv.x), f1 = bfhi(hv.x), f2 = bflo(hv.y), f3 = bfhi(hv.y);
            float f4_ = bflo(hv.z), f5 = bfhi(hv.z), f6 = bflo(hv.w), f7 = bfhi(hv.w);
            if (bias) {
                float4 b0 = *(const float4*)(bias + o);
                float4 b1 = *(const float4*)(bias + o + 4);
                f0 += b0.x; f1 += b0.y; f2 += b0.z; f3 += b0.w;
                f4_ += b1.x; f5 += b1.y; f6 += b1.z; f7 += b1.w;
            }
            if (RELU) {
                f0 = fmaxf(f0, 0.f); f1 = fmaxf(f1, 0.f); f2 = fmaxf(f2, 0.f);
                f3 = fmaxf(f3, 0.f); f4_ = fmaxf(f4_, 0.f); f5 = fmaxf(f5, 0.f);
                f6 = fmaxf(f6, 0.f); f7 = fmaxf(f7, 0.f);
            }
            uint4 pk;
            pk.x = pack2(f0, f1); pk.y = pack2(f2, f3);
            pk.z = pack2(f4_, f5); pk.w = pack2(f6, f7);
            *(uint4*)(As + r * APITCH + o) = pk;
        }
    } else {
        const float* A = (const float*)Araw;
#pragma unroll
        for (int j = 0; j < 8; ++j) {
            int c4 = tid + j * 256;            // 0..2047; 32 float4 per row
            int r  = c4 >> 5;
            int o  = (c4 & 31) << 2;
            float4 v = *(const float4*)(A + (size_t)(row0 + r) * F + o);
            if (bias) {
                v.x += bias[o + 0]; v.y += bias[o + 1];
                v.z += bias[o + 2]; v.w += bias[o + 3];
            }
            if (RELU) {
                v.x = fmaxf(v.x, 0.f); v.y = fmaxf(v.y, 0.f);
                v.z = fmaxf(v.z, 0.f); v.w = fmaxf(v.w, 0.f);
            }
            uint2 p;
            p.x = pack2(v.x, v.y);
            p.y = pack2(v.z, v.w);
            *(uint2*)(As + r * APITCH + o) = p;
        }
    }
    __syncthreads();

    const int lane = tid & 63;
    const int wave = tid >> 6;
    const int m16  = lane & 15;
    const int quad = lane >> 4;

    f32x4 acc[8];
#pragma unroll
    for (int t = 0; t < 8; ++t) acc[t] = (f32x4)(0.0f);

#pragma unroll
    for (int ks = 0; ks < 128; ks += 32) {
        bf16x8 a = *(const bf16x8*)(As + (wave * 16 + m16) * APITCH + ks + quad * 8);
#pragma unroll
        for (int t = 0; t < 8; ++t) {
            bf16x8 b = *(const bf16x8*)(Ws + (t * 16 + m16) * APITCH + ks + quad * 8);
            acc[t] = __builtin_amdgcn_mfma_f32_16x16x32_bf16(a, b, acc[t], 0, 0, 0);
        }
    }

    // Epilogue: D row = quad*4+reg, col = t*16+m16; optional dis[row] scale.
    // Stage into As rows (wave-private: wave w owns rows w*16..w*16+15, and its
    // MFMA reads of those rows are complete) -> read back -> coalesced stores.
    const int rloc = wave * 16 + quad * 4;
    float sc[4];
#pragma unroll
    for (int rg = 0; rg < 4; ++rg) sc[rg] = SCALE ? dis[row0 + rloc + rg] : 1.0f;
#pragma unroll
    for (int t = 0; t < 8; ++t) {
        int col = t * 16 + m16;
#pragma unroll
        for (int rg = 0; rg < 4; ++rg)
            As[(rloc + rg) * APITCH + col] = f2bf(acc[t][rg] * sc[rg]);
    }
    // Read back 16 rows x 256 B = 4 uint4 per lane, store coalesced.
#pragma unroll
    for (int i = 0; i < 4; ++i) {
        int idx = lane + i * 64;          // 0..255
        int r   = idx >> 4;               // 0..15
        int p   = idx & 15;               // 16B chunk
        uint4 val = *(const uint4*)(As + (wave * 16 + r) * APITCH + p * 8);
        *((uint4*)(Hb + (size_t)(row0 + wave * 16 + r) * F) + p) = val;
    }
}

// ---------------------------------------------------------------------------
// Gather aggregation v5 (bf16 H -> bf16 AGG): one wave per node; 16 edges per
// step with 4 independent uint4 gathers in flight per lane (masked; avg degree
// 16 -> typically one step); fp32 accumulate, quad shfl_xor reduction.
// SCALED=false: Hb pre-scaled by dis[row]:  AGG[v] = dis[v]*(sum Hb[src] + Hb[v])
// SCALED=true : AGG[v] = dis[v]*(sum dis[src]*Hb[src] + dis[v]*Hb[v])
template <bool SCALED>
__global__ __launch_bounds__(256) void gather_kernel(
    const unsigned short* __restrict__ Hb, const int* __restrict__ csr_src,
    const int* __restrict__ rowptr, const int* __restrict__ deg,
    const float* __restrict__ dis, unsigned short* __restrict__ AGGb) {
    const int gid  = blockIdx.x * 256 + threadIdx.x;
    const int v    = gid >> 6;
    if (v >= N_NODES) return;
    const int lane = threadIdx.x & 63;
    const int part = lane & 15;          // 16B chunk of the 256B row
    const int quad = lane >> 4;          // edge slot within group of 4

    const int start = rowptr[v];
    const int len   = deg[v];
    const uint4* Hp = (const uint4*)Hb + part;   // 16 uint4 per row

    float acc[8];
#pragma unroll
    for (int i = 0; i < 8; ++i) acc[i] = 0.f;

    for (int j0 = 0; j0 < len; j0 += 64) {
        int m = len - j0; if (m > 64) m = 64;
        int nidx = (lane < m) ? csr_src[start + j0 + lane] : 0;
        for (int j = 0; j < m; j += 16) {
            int   r[4];
            float w[4];
            uint4 h[4];
#pragma unroll
            for (int u = 0; u < 4; ++u) {
                int  sl    = j + u * 4 + quad;
                bool valid = sl < m;
                r[u] = __shfl(nidx, valid ? sl : 0, 64);
                w[u] = valid ? (SCALED ? dis[r[u]] : 1.0f) : 0.0f;
            }
#pragma unroll
            for (int u = 0; u < 4; ++u) h[u] = Hp[(size_t)r[u] * 16];
#pragma unroll
            for (int u = 0; u < 4; ++u) {
                acc[0] = fmaf(bflo(h[u].x), w[u], acc[0]);
                acc[1] = fmaf(bfhi(h[u].x), w[u], acc[1]);
                acc[2] = fmaf(bflo(h[u].y), w[u], acc[2]);
                acc[3] = fmaf(bfhi(h[u].y), w[u], acc[3]);
                acc[4] = fmaf(bflo(h[u].z), w[u], acc[4]);
                acc[5] = fmaf(bfhi(h[u].z), w[u], acc[5]);
                acc[6] = fmaf(bflo(h[u].w), w[u], acc[6]);
                acc[7] = fmaf(bfhi(h[u].w), w[u], acc[7]);
            }
        }
    }

    // combine the 4 edge-slots (same cols at lane^16, lane^32)
#pragma unroll
    for (int i = 0; i < 8; ++i) {
        acc[i] += __shfl_xor(acc[i], 16, 64);
        acc[i] += __shfl_xor(acc[i], 32, 64);
    }

    if (quad == 0) {
        float dc  = dis[v];
        float ws_ = SCALED ? dc : 1.0f;
        uint4 h = Hp[(size_t)v * 16];               // self-loop
        acc[0] = fmaf(bflo(h.x), ws_, acc[0]); acc[1] = fmaf(bfhi(h.x), ws_, acc[1]);
        acc[2] = fmaf(bflo(h.y), ws_, acc[2]); acc[3] = fmaf(bfhi(h.y), ws_, acc[3]);
        acc[4] = fmaf(bflo(h.z), ws_, acc[4]); acc[5] = fmaf(bfhi(h.z), ws_, acc[5]);
        acc[6] = fmaf(bflo(h.w), ws_, acc[6]); acc[7] = fmaf(bfhi(h.w), ws_, acc[7]);
        uint4 pk;
        pk.x = pack2(acc[0] * dc, acc[1] * dc);
        pk.y = pack2(acc[2] * dc, acc[3] * dc);
        pk.z = pack2(acc[4] * dc, acc[5] * dc);
        pk.w = pack2(acc[6] * dc, acc[7] * dc);
        *((uint4*)AGGb + (size_t)v * 16 + part) = pk;
    }
}

// ---------------------------------------------------------------------------
// Pool v3 (bf16 AGG): 400 blocks x 100 nodes; 8 row-slots x 32 lanes x 4 cols.
// pooled[g][f] += relu(AGG[v][f] + b3[f]); cnt[g] += 1. batch sorted ->
// per-slot run-length accumulate (slot's g non-decreasing), flush on change.
#define POOL_NODES 100
__global__ __launch_bounds__(256) void pool_kernel(
    const unsigned short* __restrict__ AGGb, const int* __restrict__ batch,
    const float* __restrict__ b3,
    float* __restrict__ pooled, float* __restrict__ cnt) {
    const int tid  = threadIdx.x;
    const int f4   = (tid & 31) << 2;     // 4-col group
    const int slot = tid >> 5;            // 0..7
    const int base = blockIdx.x * POOL_NODES;
    const float4 bf = *(const float4*)(b3 + f4);

    float4 acc = make_float4(0.f, 0.f, 0.f, 0.f);
    float c = 0.f;
    int gcur = -1;
    for (int j = slot; j < POOL_NODES; j += 8) {
        int v = base + j;                 // 400*100 = 40000, always in range
        int g = batch[v];
        if (g != gcur) {
            if (gcur >= 0) {
                float* dst = pooled + gcur * F + f4;
                atomicAdd(dst + 0, acc.x); atomicAdd(dst + 1, acc.y);
                atomicAdd(dst + 2, acc.z); atomicAdd(dst + 3, acc.w);
                if (f4 == 0) atomicAdd(&cnt[gcur], c);
            }
            acc = make_float4(0.f, 0.f, 0.f, 0.f); c = 0.f; gcur = g;
        }
        uint2 a = *(const uint2*)(AGGb + (size_t)v * F + f4);
        acc.x += fmaxf(bflo(a.x) + bf.x, 0.f);
        acc.y += fmaxf(bfhi(a.x) + bf.y, 0.f);
        acc.z += fmaxf(bflo(a.y) + bf.z, 0.f);
        acc.w += fmaxf(bfhi(a.y) + bf.w, 0.f);
        c += 1.f;
    }
    if (gcur >= 0) {
        float* dst = pooled + gcur * F + f4;
        atomicAdd(dst + 0, acc.x); atomicAdd(dst + 1, acc.y);
        atomicAdd(dst + 2, acc.z); atomicAdd(dst + 3, acc.w);
        if (f4 == 0) atomicAdd(&cnt[gcur], c);
    }
}

// ---------------------------------------------------------------------------
// Head: out[g][c] = (sum_f pooled[g][f] * Wl[f][c]) / max(cnt[g],1) + bl[c]
__global__ void head_kernel(const float* __restrict__ pooled,
                            const float* __restrict__ cnt,
                            const float* __restrict__ Wl,
                            const float* __restrict__ bl,
                            float* __restrict__ out) {
    int tid = threadIdx.x;
    if (tid >= N_GRAPHS * N_CLASSES) return;
    int g = tid / N_CLASSES, c = tid % N_CLASSES;
    float acc = 0.f;
    for (int ff = 0; ff < F; ++ff)
        acc += pooled[g * F + ff] * Wl[ff * N_CLASSES + c];
    out[g * N_CLASSES + c] = acc / fmaxf(cnt[g], 1.f) + bl[c];
}

// ---------------------------------------------------------------------------
extern "C" void kernel_launch(void* const* d_in, const int* in_sizes, int n_in,
                              void* d_out, int out_size, void* d_ws, size_t ws_size,
                              hipStream_t stream) {
    const float* x    = (const float*)d_in[0];
    const int*   ei   = (const int*)d_in[1];     // [2][E]
    const int*   bat  = (const int*)d_in[2];
    const float* W1   = (const float*)d_in[3];
    const float* b1   = (const float*)d_in[4];
    const float* W2   = (const float*)d_in[5];
    const float* b2   = (const float*)d_in[6];
    const float* W3   = (const float*)d_in[7];
    const float* b3   = (const float*)d_in[8];
    const float* Wl   = (const float*)d_in[9];
    const float* bl   = (const float*)d_in[10];
    float* out = (float*)d_out;

    const int* row = ei;                 // edge_index[0] (source)
    const int* col = ei + N_EDGES;       // edge_index[1] (target)

    // Workspace layout (16B-aligned chunks)
    float*          ws      = (float*)d_ws;
    float*          dis     = ws;                                     // 40000 f
    unsigned short* Hb      = (unsigned short*)(dis + N_NODES);       // 5.12M bf16
    unsigned short* AGGb    = Hb + (size_t)N_NODES * F;               // 5.12M bf16
    float*          pooled  = (float*)(AGGb + (size_t)N_NODES * F);   // 8192 f
    float*          cnt     = pooled + N_GRAPHS * F;                  // 64 f
    int*            deg     = (int*)(cnt + N_GRAPHS);                 // 40000 i
    int*            rowptr  = deg + N_NODES;                          // 40000 i
    int*            cursor  = rowptr + N_NODES;                       // 40000 i
    int*            csr_src = cursor + N_NODES;                       // 640000 i
    unsigned short* Wtb     = (unsigned short*)(csr_src + N_EDGES);   // 3*16384 bf16

    const int edgeGrid   = (N_EDGES + 255) / 256;      // 2500
    const int gemmGrid   = N_NODES / 64;               // 625
    const int gatherGrid = (N_NODES * 64) / 256;       // 10000

    // --- W convert + zero deg (one kernel) ---
    wcvt_kernel<<<192, 256, 0, stream>>>(W1, W2, W3, Wtb, deg);

    // --- layer 1 GEMM (unscaled bf16 H, fused degree count), then CSR build ---
    gemm_mfma<false, false, false, true><<<gemmGrid, 256, 0, stream>>>(
        x, Wtb, nullptr, nullptr, Hb, col, deg);
    scan_kernel<<<1, 1024, 0, stream>>>(deg, rowptr, cursor, dis, pooled);
    fill_kernel<<<edgeGrid, 256, 0, stream>>>(row, col, cursor, csr_src);
    gather_kernel<true><<<gatherGrid, 256, 0, stream>>>(Hb, csr_src, rowptr, deg, dis, AGGb);

    // --- layer 2 (relu(agg+b1) fused into staging; H pre-scaled by dis) ---
    gemm_mfma<true, true, true, false><<<gemmGrid, 256, 0, stream>>>(
        AGGb, Wtb + 16384, b1, dis, Hb, nullptr, nullptr);
    gather_kernel<false><<<gatherGrid, 256, 0, stream>>>(Hb, csr_src, rowptr, deg, dis, AGGb);

    // --- layer 3 ---
    gemm_mfma<true, true, true, false><<<gemmGrid, 256, 0, stream>>>(
        AGGb, Wtb + 32768, b2, dis, Hb, nullptr, nullptr);
    gather_kernel<false><<<gatherGrid, 256, 0, stream>>>(Hb, csr_src, rowptr, deg, dis, AGGb);

    // --- pool (fuses relu(agg + b3)) + head ---
    pool_kernel<<<N_NODES / POOL_NODES, 256, 0, stream>>>(AGGb, bat, b3, pooled, cnt);
    head_kernel<<<1, N_GRAPHS * N_CLASSES, 0, stream>>>(pooled, cnt, Wl, bl, out);
}